// Round 18
// baseline (451.307 us; speedup 1.0000x reference)
//
#include <hip/hip_runtime.h>

// 4-layer 5-point cross-stencil CNN, implicit GEMM on MFMA (MI355X gfx950).
// Round 23: r17 gmid body (1x4 oc partition, 1-deep A/B) promoted to
//   __launch_bounds__(256,3) -> 12 waves/CU (3/SIMD), +50% latency hiding
//   at identical traffic/partition/k-loop.
//   Ledger logic: unified VGPR+AGPR cap at (256,3) is ~170/wave. All five
//   spills were demand > 170 (r7: 180; r13/14/18: more). r17's body is
//   100 arch + 64 AGPR = 164 <= 170 -- it was only ever run at (256,2)
//   out of caution. r20's ring-3 (104+64=168, 2-reg margin) dropped for
//   1-deep (6-reg margin); ring-3 was worth ~1.5us and 3/SIMD cross-wave
//   hiding supersedes in-wave rings.
//   g1/g4/prep byte-identical to r20 (341.6/342.3us confirmed best).
//   Tripwire: gmid VGPR=84 or FETCH>90MB or WRITE>140MB = spill -> revert
//   to r20 as final. Null (gmid >= 92us clean) -> r20 final.
// MFMA 16x16x32_f16 layouts (verified round 3):
//   A[m=lane&15][k=quad*8+j], B[n=lane&15][k=quad*8+j], C: col=lane&15,
//   row=quad*4+reg.   Taps: 0=c,1=up,2=down,3=left,4=right.

#define BB   8
#define HH   256
#define WW   256

typedef _Float16 f16x8 __attribute__((ext_vector_type(8)));
typedef float    f32x4 __attribute__((ext_vector_type(4)));

// K-major fp16 weight tables (rewritten every launch by prep).
__device__ _Float16 W1g[128 * 32];       // [oc][k], k=tap*6+ic, 30..31 = 0
__device__ _Float16 W2g[20 * 128 * 32];  // [ks=tap*4+kc][oc][icb]
__device__ _Float16 W3g[20 * 128 * 32];
__device__ _Float16 W4g[5 * 16 * 128];   // [tap][oc(pad16)][ic]

__global__ void prep(const float* __restrict__ w1, const float* __restrict__ w2,
                     const float* __restrict__ w3, const float* __restrict__ w4)
{
    int idx = blockIdx.x * 256 + threadIdx.x;
    if (idx < 81920) {                                  // W2g
        int icb = idx & 31, oc = (idx >> 5) & 127, ks = idx >> 12;
        int tap = ks >> 2, ic = (ks & 3) * 32 + icb;
        W2g[idx] = (_Float16)w2[(oc * 128 + ic) * 5 + tap];
    } else if (idx < 163840) {                          // W3g
        int k = idx - 81920;
        int icb = k & 31, oc = (k >> 5) & 127, ks = k >> 12;
        int tap = ks >> 2, ic = (ks & 3) * 32 + icb;
        W3g[k] = (_Float16)w3[(oc * 128 + ic) * 5 + tap];
    } else if (idx < 174080) {                          // W4g
        int k = idx - 163840;
        int t = k / 2048, oc = (k >> 7) & 15, ic = k & 127;
        W4g[k] = (_Float16)((oc < 6) ? w4[(oc * 128 + ic) * 5 + t] : 0.f);
    } else if (idx < 178176) {                          // W1g
        int k = idx - 174080;
        int kk = k & 31, oc = k >> 5;
        float v = 0.f;
        if (kk < 30) {
            int tap = (kk * 43) >> 8;                   // kk/6 for kk<30
            int ic = kk - 6 * tap;
            v = w1[(oc * 6 + ic) * 5 + tap];
        }
        W1g[k] = (_Float16)v;
    }
}

// ---------------- L1: MFMA, K=32 (tap*6+ic, padded). NCHW fp32 -> NHWC fp16.
// Staging planes k=2*it+HALF: HALF wave-uniform -> tap/ic/di/dj compile-time.
template<int HALF, bool EDGE>
__device__ __forceinline__ void g1_stage(const float* __restrict__ xb,
                                         _Float16* __restrict__ Ap,
                                         int px, int gi0, int gj0)
{
#pragma unroll
    for (int it = 0; it < 15; ++it) {
        const int k = 2 * it + HALF;                    // compile-time
        const int tap = k / 6, ic = k - 6 * tap;
        const int DI = (tap == 1) ? -1 : ((tap == 2) ? 1 : 0);
        const int DJ = (tap == 3) ? -1 : ((tap == 4) ? 1 : 0);
        const float* sp = xb + ic * 65536 + DI * 256 + DJ;
        float v;
        if (EDGE) {
            const int gi = gi0 + DI, gj = gj0 + DJ;
            v = ((unsigned)gi < 256u && (unsigned)gj < 256u) ? *sp : 0.f;
        } else {
            v = *sp;
        }
        Ap[px * 40 + k] = (_Float16)v;
    }
    Ap[px * 40 + 30 + HALF] = (_Float16)0.f;            // K-pad 30/31
}

__global__ __launch_bounds__(256, 3) void g1(
    const float* __restrict__ x, const float* __restrict__ bias,
    _Float16* __restrict__ outp)
{
    __shared__ _Float16 Ap[128 * 40];
    const int tid = threadIdx.x;
    const int j0 = blockIdx.x * 16, i0 = blockIdx.y * 8, b = blockIdx.z;
    const int px = tid & 127, half = tid >> 7;
    const int pr = px >> 4, pp = px & 15;
    const bool edge = (blockIdx.y == 0) | (blockIdx.y == 31) |
                      (blockIdx.x == 0) | (blockIdx.x == 15);
    const int gi0 = i0 + pr, gj0 = j0 + pp;
    const float* xb = x + (size_t)b * 6 * 65536 + gi0 * 256 + gj0;

    if (edge) {
        if (half == 0) g1_stage<0, true >(xb, Ap, px, gi0, gj0);
        else           g1_stage<1, true >(xb, Ap, px, gi0, gj0);
    } else {
        if (half == 0) g1_stage<0, false>(xb, Ap, px, gi0, gj0);
        else           g1_stage<1, false>(xb, Ap, px, gi0, gj0);
    }
    __syncthreads();

    const int lane = tid & 63, w = tid >> 6, l16 = lane & 15, quad = lane >> 4;
    f32x4 acc[2][8] = {};
    f16x8 a0 = *(const f16x8*)&Ap[((2 * w + 0) * 16 + l16) * 40 + quad * 8];
    f16x8 a1 = *(const f16x8*)&Ap[((2 * w + 1) * 16 + l16) * 40 + quad * 8];
#pragma unroll
    for (int nf = 0; nf < 8; ++nf) {
        f16x8 bf = *(const f16x8*)&W1g[(nf * 16 + l16) * 32 + quad * 8];
        acc[0][nf] = __builtin_amdgcn_mfma_f32_16x16x32_f16(a0, bf, acc[0][nf], 0, 0, 0);
        acc[1][nf] = __builtin_amdgcn_mfma_f32_16x16x32_f16(a1, bf, acc[1][nf], 0, 0, 0);
    }
#pragma unroll
    for (int mf = 0; mf < 2; ++mf) {
        const size_t rowb = ((size_t)b * 256 + i0 + 2 * w + mf) * 256 + j0;
#pragma unroll
        for (int nf = 0; nf < 8; ++nf) {
            const float bv = bias[nf * 16 + l16];
#pragma unroll
            for (int r = 0; r < 4; ++r)
                outp[(rowb + quad * 4 + r) * 128 + nf * 16 + l16] =
                    (_Float16)fmaxf(acc[mf][nf][r] + bv, 0.f);
        }
    }
}

// ---------------- middle layers: M=128 (8 rows x 16 px), N=128, K=640 -------
// 1x4 wave grid: wave w owns ALL 8 rows and oc 32w..32w+31 (B frags distinct
// across waves -> 160KB/block B L2 traffic). Staging: 45 global_load_lds(16B)
// into linear LDS [180][128], source-side XOR swizzle. 1-deep A/B prefetch.
// bounds(256,3): 100 arch + 64 AGPR = 164 <= 170 cap -> 3 blocks/CU.
template<int LAYER>
__global__ __launch_bounds__(256, 3) void gmid(
    const _Float16* __restrict__ in, const float* __restrict__ bias,
    _Float16* __restrict__ outp)
{
    const _Float16* wt = (LAYER == 2) ? W2g : W3g;
    __shared__ __align__(16) _Float16 Al[180 * 128];    // 46080 B, linear
    const int tid = threadIdx.x;
    const int lane = tid & 63, w = tid >> 6;
    const int j0 = blockIdx.x * 16, i0 = blockIdx.y * 8, b = blockIdx.z;
    const bool top = (blockIdx.y == 0), bot = (blockIdx.y == 31);
    const bool left = (blockIdx.x == 0), right = (blockIdx.x == 15);

    {
        const int pxl = lane & 15;
#pragma unroll
        for (int k = 0; k < 12; ++k) {
            const int m = w + 4 * k;
            if (m < 45) {
                const int s = 4 * m + (lane >> 4);
                const int r = (s * 114) >> 11;          // s/18 for s<288
                const int p = s - 18 * r;
                int gi = i0 - 1 + r; gi = gi < 0 ? 0 : (gi > 255 ? 255 : gi);
                int gj = j0 - 1 + p; gj = gj < 0 ? 0 : (gj > 255 ? 255 : gj);
                const _Float16* src = in + (((size_t)(b * 256 + gi)) * 256 + gj) * 128
                                         + ((pxl ^ (s & 7)) << 3);
                __builtin_amdgcn_global_load_lds(
                    (const __attribute__((address_space(1))) void*)src,
                    (__attribute__((address_space(3))) void*)(Al + m * 512),
                    16, 0, 0);
            }
        }
    }
    __syncthreads();
    if (top | bot | left | right) {                     // zero clamp-loaded halo
#pragma unroll
        for (int pass = 0; pass < 2; ++pass) {
            const int gidx = (tid >> 3) + 32 * pass, c = tid & 7;
            int sid = -1;
            if (gidx < 18)      { if (top)   sid = gidx; }             // r=0
            else if (gidx < 36) { if (bot)   sid = 162 + gidx - 18; }  // r=9
            else if (gidx < 46) { if (left)  sid = (gidx - 36) * 18; }        // p=0
            else if (gidx < 56) { if (right) sid = (gidx - 46) * 18 + 17; }   // p=17
            if (sid >= 0) {
                const f16x8 z = {};
                *(f16x8*)(Al + sid * 128 + c * 16)     = z;
                *(f16x8*)(Al + sid * 128 + c * 16 + 8) = z;
            }
        }
        __syncthreads();
    }

    const int l16 = lane & 15, quad = lane >> 4;
    const int n0 = w * 32;                       // wave's 32 oc (distinct)

    const _Float16* wb = wt + (size_t)(n0 + l16) * 32 + quad * 8;
    // B frag (ks, nf) at wb + ks*4096 + nf*512

    f32x4 acc[8][2] = {};
    const int DR[5] = {1, 0, 2, 1, 1}, DP[5] = {1, 1, 1, 0, 2};

    // A-frag read: site s, chunk c = kc*4+quad, stored at c^(s&7)
    auto lda = [&](int ks, int r) -> f16x8 {
        const int tap = ks >> 2, kc = ks & 3;
        const int s = (DR[tap] + r) * 18 + DP[tap] + l16;
        const int ch = (kc * 4 + quad) ^ (s & 7);
        return *(const f16x8*)&Al[s * 128 + ch * 8];
    };

    f16x8 bc[2], bn[2], ac[8], an[8];
#pragma unroll
    for (int nf = 0; nf < 2; ++nf) bc[nf] = *(const f16x8*)(wb + nf * 512);
#pragma unroll
    for (int r = 0; r < 8; ++r) ac[r] = lda(0, r);

#pragma unroll
    for (int ks = 0; ks < 20; ++ks) {
        if (ks < 19) {
#pragma unroll
            for (int nf = 0; nf < 2; ++nf)
                bn[nf] = *(const f16x8*)(wb + (size_t)(ks + 1) * 4096 + nf * 512);
#pragma unroll
            for (int r = 0; r < 8; ++r) an[r] = lda(ks + 1, r);
        }
        __builtin_amdgcn_s_setprio(1);
#pragma unroll
        for (int r = 0; r < 8; ++r)
#pragma unroll
            for (int nf = 0; nf < 2; ++nf)
                acc[r][nf] = __builtin_amdgcn_mfma_f32_16x16x32_f16(
                    ac[r], bc[nf], acc[r][nf], 0, 0, 0);
        __builtin_amdgcn_s_setprio(0);
#pragma unroll
        for (int nf = 0; nf < 2; ++nf) bc[nf] = bn[nf];
#pragma unroll
        for (int r = 0; r < 8; ++r) ac[r] = an[r];
    }

#pragma unroll
    for (int r = 0; r < 8; ++r) {
        const size_t rowb = ((size_t)b * 256 + i0 + r) * 256 + j0;
#pragma unroll
        for (int nf = 0; nf < 2; ++nf) {
            const float bv = bias[n0 + nf * 16 + l16];
#pragma unroll
            for (int vi = 0; vi < 4; ++vi)
                outp[(rowb + quad * 4 + vi) * 128 + n0 + nf * 16 + l16] =
                    (_Float16)fmaxf(acc[r][nf][vi] + bv, 0.f);
        }
    }
}

// ---------------- L4: 128 -> 6 (pad 16), gmid-style tiles + gload_lds -------
// 8-row x 16-px tile (grid 16x32x8). Staging/fixup identical to round-9 gmid.
// M = 128 px (8 frags of 16), N = 16 (6 oc + pad), K = 640.
// Wave w computes M-frags {2w, 2w+1} (rows 2w, 2w+1). 40 MFMA/wave.
// 1-deep prefetch of (bf, af0, af1) across the k-loop.
__global__ __launch_bounds__(256, 3) void g4(
    const _Float16* __restrict__ in, const float* __restrict__ bias,
    float* __restrict__ outp)
{
    __shared__ __align__(16) _Float16 Al[180 * 128];    // 46080 B, linear
    const int tid = threadIdx.x;
    const int lane = tid & 63, w = tid >> 6;
    const int j0 = blockIdx.x * 16, i0 = blockIdx.y * 8, b = blockIdx.z;
    const bool top = (blockIdx.y == 0), bot = (blockIdx.y == 31);
    const bool left = (blockIdx.x == 0), right = (blockIdx.x == 15);

    {
        const int pxl = lane & 15;
#pragma unroll
        for (int k = 0; k < 12; ++k) {
            const int m = w + 4 * k;
            if (m < 45) {
                const int s = 4 * m + (lane >> 4);
                const int r = (s * 114) >> 11;          // s/18 for s<288
                const int p = s - 18 * r;
                int gi = i0 - 1 + r; gi = gi < 0 ? 0 : (gi > 255 ? 255 : gi);
                int gj = j0 - 1 + p; gj = gj < 0 ? 0 : (gj > 255 ? 255 : gj);
                const _Float16* src = in + (((size_t)(b * 256 + gi)) * 256 + gj) * 128
                                         + ((pxl ^ (s & 7)) << 3);
                __builtin_amdgcn_global_load_lds(
                    (const __attribute__((address_space(1))) void*)src,
                    (__attribute__((address_space(3))) void*)(Al + m * 512),
                    16, 0, 0);
            }
        }
    }
    __syncthreads();
    if (top | bot | left | right) {                     // zero clamp-loaded halo
#pragma unroll
        for (int pass = 0; pass < 2; ++pass) {
            const int gidx = (tid >> 3) + 32 * pass, c = tid & 7;
            int sid = -1;
            if (gidx < 18)      { if (top)   sid = gidx; }             // r=0
            else if (gidx < 36) { if (bot)   sid = 162 + gidx - 18; }  // r=9
            else if (gidx < 46) { if (left)  sid = (gidx - 36) * 18; }        // p=0
            else if (gidx < 56) { if (right) sid = (gidx - 46) * 18 + 17; }   // p=17
            if (sid >= 0) {
                const f16x8 z = {};
                *(f16x8*)(Al + sid * 128 + c * 16)     = z;
                *(f16x8*)(Al + sid * 128 + c * 16 + 8) = z;
            }
        }
        __syncthreads();
    }

    const int l16 = lane & 15, quad = lane >> 4;
    const int DR[5] = {1, 0, 2, 1, 1}, DP[5] = {1, 1, 1, 0, 2};

    auto lda = [&](int ks, int row) -> f16x8 {
        const int tap = ks >> 2, kc = ks & 3;
        const int s = (DR[tap] + row) * 18 + DP[tap] + l16;
        const int ch = (kc * 4 + quad) ^ (s & 7);
        return *(const f16x8*)&Al[s * 128 + ch * 8];
    };
    auto ldb = [&](int ks) -> f16x8 {
        const int tap = ks >> 2, kc = ks & 3;
        return *(const f16x8*)&W4g[(size_t)(tap * 16 + l16) * 128 + kc * 32 + quad * 8];
    };

    f32x4 acc[2] = {};
    f16x8 bfc = ldb(0), bfn;
    f16x8 afc0 = lda(0, 2 * w), afc1 = lda(0, 2 * w + 1), afn0, afn1;
#pragma unroll
    for (int ks = 0; ks < 20; ++ks) {
        if (ks < 19) {
            bfn  = ldb(ks + 1);
            afn0 = lda(ks + 1, 2 * w);
            afn1 = lda(ks + 1, 2 * w + 1);
        }
        __builtin_amdgcn_s_setprio(1);
        acc[0] = __builtin_amdgcn_mfma_f32_16x16x32_f16(afc0, bfc, acc[0], 0, 0, 0);
        acc[1] = __builtin_amdgcn_mfma_f32_16x16x32_f16(afc1, bfc, acc[1], 0, 0, 0);
        __builtin_amdgcn_s_setprio(0);
        bfc = bfn; afc0 = afn0; afc1 = afn1;
    }

    if (l16 < 6) {
        const float bb = bias[l16];
#pragma unroll
        for (int f = 0; f < 2; ++f) {
            const int i = i0 + 2 * w + f;
#pragma unroll
            for (int vi = 0; vi < 4; ++vi) {
                int jj = j0 + quad * 4 + vi;
                outp[(((size_t)b * 6 + l16) << 16) + i * 256 + jj] = acc[f][vi] + bb;
            }
        }
    }
}

extern "C" void kernel_launch(void* const* d_in, const int* in_sizes, int n_in,
                              void* d_out, int out_size, void* d_ws, size_t ws_size,
                              hipStream_t stream) {
    const float* x  = (const float*)d_in[0];
    const float* w1 = (const float*)d_in[1];
    const float* b1 = (const float*)d_in[2];
    const float* w2 = (const float*)d_in[3];
    const float* b2 = (const float*)d_in[4];
    const float* w3 = (const float*)d_in[5];
    const float* b3 = (const float*)d_in[6];
    const float* w4 = (const float*)d_in[7];
    const float* b4 = (const float*)d_in[8];
    float* out = (float*)d_out;

    const size_t act = (size_t)BB * HH * WW * 128;
    _Float16* A1 = (_Float16*)d_ws;
    _Float16* A2 = A1 + act;                    // exactly 268435456 B total

    prep<<<696, 256, 0, stream>>>(w1, w2, w3, w4);
    dim3 blk(256, 1, 1);
    dim3 gm(16, 32, 8);                         // 16-px x 8-row tiles
    g1<<<gm, blk, 0, stream>>>(x, b1, A1);
    gmid<2><<<gm, blk, 0, stream>>>(A1, b2, A2);
    gmid<3><<<gm, blk, 0, stream>>>(A2, b3, A1);
    g4<<<gm, blk, 0, stream>>>(A1, b4, out);
}

// Round 19
// 339.772 us; speedup vs baseline: 1.3283x; 1.3283x over previous
//
#include <hip/hip_runtime.h>

// 4-layer 5-point cross-stencil CNN, implicit GEMM on MFMA (MI355X gfx950).
// FINAL (round 24) = round-20 verbatim, harness-verified twice at
//   341.6us (r15 run) / 342.3us (r17 run). r23's (256,3) promotion spilled
//   (VGPR clipped to 84, FETCH 148MB, WRITE 276MB, 451us) -- 6th and final
//   proof that this body fits only at launch_bounds(256,2).
// Session ledger (519.5 -> 341.6us, -34%):
//   WIN  r9  gmid global_load_lds staging + setprio   178 -> 128us/dispatch
//   WIN  r10 g4 gmid-style retile                     419 -> 390 total
//   WIN  r17 1x4 oc partition (halve B L2 traffic)    121 -> 95.7us
//   WIN  r20 ring-3 B at bounds(256,2)                94.5 -> 93us
//   CLOSED occupancy (spill x6), stage-drain overlap (spill x5),
//          32x32 MFMA (-9%), g1 rewrites (+6us), 2x-wave TLP (-4%).
// gmid residual: barrier-serialized 46KB stage drain -- unhideable at HIP
// source level on this compiler (needs hand-asm counted-vmcnt K-loop).
// MFMA 16x16x32_f16 layouts (verified round 3):
//   A[m=lane&15][k=quad*8+j], B[n=lane&15][k=quad*8+j], C: col=lane&15,
//   row=quad*4+reg.   Taps: 0=c,1=up,2=down,3=left,4=right.

#define BB   8
#define HH   256
#define WW   256

typedef _Float16 f16x8 __attribute__((ext_vector_type(8)));
typedef float    f32x4 __attribute__((ext_vector_type(4)));

// K-major fp16 weight tables (rewritten every launch by prep).
__device__ _Float16 W1g[128 * 32];       // [oc][k], k=tap*6+ic, 30..31 = 0
__device__ _Float16 W2g[20 * 128 * 32];  // [ks=tap*4+kc][oc][icb]
__device__ _Float16 W3g[20 * 128 * 32];
__device__ _Float16 W4g[5 * 16 * 128];   // [tap][oc(pad16)][ic]

__global__ void prep(const float* __restrict__ w1, const float* __restrict__ w2,
                     const float* __restrict__ w3, const float* __restrict__ w4)
{
    int idx = blockIdx.x * 256 + threadIdx.x;
    if (idx < 81920) {                                  // W2g
        int icb = idx & 31, oc = (idx >> 5) & 127, ks = idx >> 12;
        int tap = ks >> 2, ic = (ks & 3) * 32 + icb;
        W2g[idx] = (_Float16)w2[(oc * 128 + ic) * 5 + tap];
    } else if (idx < 163840) {                          // W3g
        int k = idx - 81920;
        int icb = k & 31, oc = (k >> 5) & 127, ks = k >> 12;
        int tap = ks >> 2, ic = (ks & 3) * 32 + icb;
        W3g[k] = (_Float16)w3[(oc * 128 + ic) * 5 + tap];
    } else if (idx < 174080) {                          // W4g
        int k = idx - 163840;
        int t = k / 2048, oc = (k >> 7) & 15, ic = k & 127;
        W4g[k] = (_Float16)((oc < 6) ? w4[(oc * 128 + ic) * 5 + t] : 0.f);
    } else if (idx < 178176) {                          // W1g
        int k = idx - 174080;
        int kk = k & 31, oc = k >> 5;
        float v = 0.f;
        if (kk < 30) {
            int tap = (kk * 43) >> 8;                   // kk/6 for kk<30
            int ic = kk - 6 * tap;
            v = w1[(oc * 6 + ic) * 5 + tap];
        }
        W1g[k] = (_Float16)v;
    }
}

// ---------------- L1: MFMA, K=32 (tap*6+ic, padded). NCHW fp32 -> NHWC fp16.
// Staging planes k=2*it+HALF: HALF wave-uniform -> tap/ic/di/dj compile-time.
template<int HALF, bool EDGE>
__device__ __forceinline__ void g1_stage(const float* __restrict__ xb,
                                         _Float16* __restrict__ Ap,
                                         int px, int gi0, int gj0)
{
#pragma unroll
    for (int it = 0; it < 15; ++it) {
        const int k = 2 * it + HALF;                    // compile-time
        const int tap = k / 6, ic = k - 6 * tap;
        const int DI = (tap == 1) ? -1 : ((tap == 2) ? 1 : 0);
        const int DJ = (tap == 3) ? -1 : ((tap == 4) ? 1 : 0);
        const float* sp = xb + ic * 65536 + DI * 256 + DJ;
        float v;
        if (EDGE) {
            const int gi = gi0 + DI, gj = gj0 + DJ;
            v = ((unsigned)gi < 256u && (unsigned)gj < 256u) ? *sp : 0.f;
        } else {
            v = *sp;
        }
        Ap[px * 40 + k] = (_Float16)v;
    }
    Ap[px * 40 + 30 + HALF] = (_Float16)0.f;            // K-pad 30/31
}

__global__ __launch_bounds__(256, 3) void g1(
    const float* __restrict__ x, const float* __restrict__ bias,
    _Float16* __restrict__ outp)
{
    __shared__ _Float16 Ap[128 * 40];
    const int tid = threadIdx.x;
    const int j0 = blockIdx.x * 16, i0 = blockIdx.y * 8, b = blockIdx.z;
    const int px = tid & 127, half = tid >> 7;
    const int pr = px >> 4, pp = px & 15;
    const bool edge = (blockIdx.y == 0) | (blockIdx.y == 31) |
                      (blockIdx.x == 0) | (blockIdx.x == 15);
    const int gi0 = i0 + pr, gj0 = j0 + pp;
    const float* xb = x + (size_t)b * 6 * 65536 + gi0 * 256 + gj0;

    if (edge) {
        if (half == 0) g1_stage<0, true >(xb, Ap, px, gi0, gj0);
        else           g1_stage<1, true >(xb, Ap, px, gi0, gj0);
    } else {
        if (half == 0) g1_stage<0, false>(xb, Ap, px, gi0, gj0);
        else           g1_stage<1, false>(xb, Ap, px, gi0, gj0);
    }
    __syncthreads();

    const int lane = tid & 63, w = tid >> 6, l16 = lane & 15, quad = lane >> 4;
    f32x4 acc[2][8] = {};
    f16x8 a0 = *(const f16x8*)&Ap[((2 * w + 0) * 16 + l16) * 40 + quad * 8];
    f16x8 a1 = *(const f16x8*)&Ap[((2 * w + 1) * 16 + l16) * 40 + quad * 8];
#pragma unroll
    for (int nf = 0; nf < 8; ++nf) {
        f16x8 bf = *(const f16x8*)&W1g[(nf * 16 + l16) * 32 + quad * 8];
        acc[0][nf] = __builtin_amdgcn_mfma_f32_16x16x32_f16(a0, bf, acc[0][nf], 0, 0, 0);
        acc[1][nf] = __builtin_amdgcn_mfma_f32_16x16x32_f16(a1, bf, acc[1][nf], 0, 0, 0);
    }
#pragma unroll
    for (int mf = 0; mf < 2; ++mf) {
        const size_t rowb = ((size_t)b * 256 + i0 + 2 * w + mf) * 256 + j0;
#pragma unroll
        for (int nf = 0; nf < 8; ++nf) {
            const float bv = bias[nf * 16 + l16];
#pragma unroll
            for (int r = 0; r < 4; ++r)
                outp[(rowb + quad * 4 + r) * 128 + nf * 16 + l16] =
                    (_Float16)fmaxf(acc[mf][nf][r] + bv, 0.f);
        }
    }
}

// ---------------- middle layers: M=128 (8 rows x 16 px), N=128, K=640 -------
// 1x4 wave grid: wave w owns ALL 8 rows and oc 32w..32w+31 (B frags distinct
// across waves -> 160KB/block B L2 traffic). Staging: 45 global_load_lds(16B)
// into linear LDS [180][128], source-side XOR swizzle. Ring-3 B, 1-deep A.
template<int LAYER>
__global__ __launch_bounds__(256, 2) void gmid(
    const _Float16* __restrict__ in, const float* __restrict__ bias,
    _Float16* __restrict__ outp)
{
    const _Float16* wt = (LAYER == 2) ? W2g : W3g;
    __shared__ __align__(16) _Float16 Al[180 * 128];    // 46080 B, linear
    const int tid = threadIdx.x;
    const int lane = tid & 63, w = tid >> 6;
    const int j0 = blockIdx.x * 16, i0 = blockIdx.y * 8, b = blockIdx.z;
    const bool top = (blockIdx.y == 0), bot = (blockIdx.y == 31);
    const bool left = (blockIdx.x == 0), right = (blockIdx.x == 15);

    {
        const int pxl = lane & 15;
#pragma unroll
        for (int k = 0; k < 12; ++k) {
            const int m = w + 4 * k;
            if (m < 45) {
                const int s = 4 * m + (lane >> 4);
                const int r = (s * 114) >> 11;          // s/18 for s<288
                const int p = s - 18 * r;
                int gi = i0 - 1 + r; gi = gi < 0 ? 0 : (gi > 255 ? 255 : gi);
                int gj = j0 - 1 + p; gj = gj < 0 ? 0 : (gj > 255 ? 255 : gj);
                const _Float16* src = in + (((size_t)(b * 256 + gi)) * 256 + gj) * 128
                                         + ((pxl ^ (s & 7)) << 3);
                __builtin_amdgcn_global_load_lds(
                    (const __attribute__((address_space(1))) void*)src,
                    (__attribute__((address_space(3))) void*)(Al + m * 512),
                    16, 0, 0);
            }
        }
    }
    __syncthreads();
    if (top | bot | left | right) {                     // zero clamp-loaded halo
#pragma unroll
        for (int pass = 0; pass < 2; ++pass) {
            const int gidx = (tid >> 3) + 32 * pass, c = tid & 7;
            int sid = -1;
            if (gidx < 18)      { if (top)   sid = gidx; }             // r=0
            else if (gidx < 36) { if (bot)   sid = 162 + gidx - 18; }  // r=9
            else if (gidx < 46) { if (left)  sid = (gidx - 36) * 18; }        // p=0
            else if (gidx < 56) { if (right) sid = (gidx - 46) * 18 + 17; }   // p=17
            if (sid >= 0) {
                const f16x8 z = {};
                *(f16x8*)(Al + sid * 128 + c * 16)     = z;
                *(f16x8*)(Al + sid * 128 + c * 16 + 8) = z;
            }
        }
        __syncthreads();
    }

    const int l16 = lane & 15, quad = lane >> 4;
    const int n0 = w * 32;                       // wave's 32 oc (distinct)

    const _Float16* wb = wt + (size_t)(n0 + l16) * 32 + quad * 8;
    // B frag (ks, nf) at wb + ks*4096 + nf*512

    f32x4 acc[8][2] = {};
    const int DR[5] = {1, 0, 2, 1, 1}, DP[5] = {1, 1, 1, 0, 2};

    // A-frag read: site s, chunk c = kc*4+quad, stored at c^(s&7)
    auto lda = [&](int ks, int r) -> f16x8 {
        const int tap = ks >> 2, kc = ks & 3;
        const int s = (DR[tap] + r) * 18 + DP[tap] + l16;
        const int ch = (kc * 4 + quad) ^ (s & 7);
        return *(const f16x8*)&Al[s * 128 + ch * 8];
    };

    f16x8 br[3][2], ac[8], an[8];
#pragma unroll
    for (int pk = 0; pk < 2; ++pk)
#pragma unroll
        for (int nf = 0; nf < 2; ++nf)
            br[pk][nf] = *(const f16x8*)(wb + (size_t)pk * 4096 + nf * 512);
#pragma unroll
    for (int r = 0; r < 8; ++r) ac[r] = lda(0, r);

#pragma unroll
    for (int ks = 0; ks < 20; ++ks) {
        if (ks + 2 < 20) {                       // B two iterations ahead
#pragma unroll
            for (int nf = 0; nf < 2; ++nf)
                br[(ks + 2) % 3][nf] =
                    *(const f16x8*)(wb + (size_t)(ks + 2) * 4096 + nf * 512);
        }
        if (ks + 1 < 20) {                       // A one iteration ahead
#pragma unroll
            for (int r = 0; r < 8; ++r) an[r] = lda(ks + 1, r);
        }
        __builtin_amdgcn_s_setprio(1);
#pragma unroll
        for (int r = 0; r < 8; ++r)
#pragma unroll
            for (int nf = 0; nf < 2; ++nf)
                acc[r][nf] = __builtin_amdgcn_mfma_f32_16x16x32_f16(
                    ac[r], br[ks % 3][nf], acc[r][nf], 0, 0, 0);
        __builtin_amdgcn_s_setprio(0);
#pragma unroll
        for (int r = 0; r < 8; ++r) ac[r] = an[r];
    }

#pragma unroll
    for (int r = 0; r < 8; ++r) {
        const size_t rowb = ((size_t)b * 256 + i0 + r) * 256 + j0;
#pragma unroll
        for (int nf = 0; nf < 2; ++nf) {
            const float bv = bias[n0 + nf * 16 + l16];
#pragma unroll
            for (int vi = 0; vi < 4; ++vi)
                outp[(rowb + quad * 4 + vi) * 128 + n0 + nf * 16 + l16] =
                    (_Float16)fmaxf(acc[r][nf][vi] + bv, 0.f);
        }
    }
}

// ---------------- L4: 128 -> 6 (pad 16), gmid-style tiles + gload_lds -------
// 8-row x 16-px tile (grid 16x32x8). Staging/fixup identical to round-9 gmid.
// M = 128 px (8 frags of 16), N = 16 (6 oc + pad), K = 640.
// Wave w computes M-frags {2w, 2w+1} (rows 2w, 2w+1). 40 MFMA/wave.
// 1-deep prefetch of (bf, af0, af1) across the k-loop.
__global__ __launch_bounds__(256, 3) void g4(
    const _Float16* __restrict__ in, const float* __restrict__ bias,
    float* __restrict__ outp)
{
    __shared__ __align__(16) _Float16 Al[180 * 128];    // 46080 B, linear
    const int tid = threadIdx.x;
    const int lane = tid & 63, w = tid >> 6;
    const int j0 = blockIdx.x * 16, i0 = blockIdx.y * 8, b = blockIdx.z;
    const bool top = (blockIdx.y == 0), bot = (blockIdx.y == 31);
    const bool left = (blockIdx.x == 0), right = (blockIdx.x == 15);

    {
        const int pxl = lane & 15;
#pragma unroll
        for (int k = 0; k < 12; ++k) {
            const int m = w + 4 * k;
            if (m < 45) {
                const int s = 4 * m + (lane >> 4);
                const int r = (s * 114) >> 11;          // s/18 for s<288
                const int p = s - 18 * r;
                int gi = i0 - 1 + r; gi = gi < 0 ? 0 : (gi > 255 ? 255 : gi);
                int gj = j0 - 1 + p; gj = gj < 0 ? 0 : (gj > 255 ? 255 : gj);
                const _Float16* src = in + (((size_t)(b * 256 + gi)) * 256 + gj) * 128
                                         + ((pxl ^ (s & 7)) << 3);
                __builtin_amdgcn_global_load_lds(
                    (const __attribute__((address_space(1))) void*)src,
                    (__attribute__((address_space(3))) void*)(Al + m * 512),
                    16, 0, 0);
            }
        }
    }
    __syncthreads();
    if (top | bot | left | right) {                     // zero clamp-loaded halo
#pragma unroll
        for (int pass = 0; pass < 2; ++pass) {
            const int gidx = (tid >> 3) + 32 * pass, c = tid & 7;
            int sid = -1;
            if (gidx < 18)      { if (top)   sid = gidx; }             // r=0
            else if (gidx < 36) { if (bot)   sid = 162 + gidx - 18; }  // r=9
            else if (gidx < 46) { if (left)  sid = (gidx - 36) * 18; }        // p=0
            else if (gidx < 56) { if (right) sid = (gidx - 46) * 18 + 17; }   // p=17
            if (sid >= 0) {
                const f16x8 z = {};
                *(f16x8*)(Al + sid * 128 + c * 16)     = z;
                *(f16x8*)(Al + sid * 128 + c * 16 + 8) = z;
            }
        }
        __syncthreads();
    }

    const int l16 = lane & 15, quad = lane >> 4;
    const int DR[5] = {1, 0, 2, 1, 1}, DP[5] = {1, 1, 1, 0, 2};

    auto lda = [&](int ks, int row) -> f16x8 {
        const int tap = ks >> 2, kc = ks & 3;
        const int s = (DR[tap] + row) * 18 + DP[tap] + l16;
        const int ch = (kc * 4 + quad) ^ (s & 7);
        return *(const f16x8*)&Al[s * 128 + ch * 8];
    };
    auto ldb = [&](int ks) -> f16x8 {
        const int tap = ks >> 2, kc = ks & 3;
        return *(const f16x8*)&W4g[(size_t)(tap * 16 + l16) * 128 + kc * 32 + quad * 8];
    };

    f32x4 acc[2] = {};
    f16x8 bfc = ldb(0), bfn;
    f16x8 afc0 = lda(0, 2 * w), afc1 = lda(0, 2 * w + 1), afn0, afn1;
#pragma unroll
    for (int ks = 0; ks < 20; ++ks) {
        if (ks < 19) {
            bfn  = ldb(ks + 1);
            afn0 = lda(ks + 1, 2 * w);
            afn1 = lda(ks + 1, 2 * w + 1);
        }
        __builtin_amdgcn_s_setprio(1);
        acc[0] = __builtin_amdgcn_mfma_f32_16x16x32_f16(afc0, bfc, acc[0], 0, 0, 0);
        acc[1] = __builtin_amdgcn_mfma_f32_16x16x32_f16(afc1, bfc, acc[1], 0, 0, 0);
        __builtin_amdgcn_s_setprio(0);
        bfc = bfn; afc0 = afn0; afc1 = afn1;
    }

    if (l16 < 6) {
        const float bb = bias[l16];
#pragma unroll
        for (int f = 0; f < 2; ++f) {
            const int i = i0 + 2 * w + f;
#pragma unroll
            for (int vi = 0; vi < 4; ++vi) {
                int jj = j0 + quad * 4 + vi;
                outp[(((size_t)b * 6 + l16) << 16) + i * 256 + jj] = acc[f][vi] + bb;
            }
        }
    }
}

extern "C" void kernel_launch(void* const* d_in, const int* in_sizes, int n_in,
                              void* d_out, int out_size, void* d_ws, size_t ws_size,
                              hipStream_t stream) {
    const float* x  = (const float*)d_in[0];
    const float* w1 = (const float*)d_in[1];
    const float* b1 = (const float*)d_in[2];
    const float* w2 = (const float*)d_in[3];
    const float* b2 = (const float*)d_in[4];
    const float* w3 = (const float*)d_in[5];
    const float* b3 = (const float*)d_in[6];
    const float* w4 = (const float*)d_in[7];
    const float* b4 = (const float*)d_in[8];
    float* out = (float*)d_out;

    const size_t act = (size_t)BB * HH * WW * 128;
    _Float16* A1 = (_Float16*)d_ws;
    _Float16* A2 = A1 + act;                    // exactly 268435456 B total

    prep<<<696, 256, 0, stream>>>(w1, w2, w3, w4);
    dim3 blk(256, 1, 1);
    dim3 gm(16, 32, 8);                         // 16-px x 8-row tiles
    g1<<<gm, blk, 0, stream>>>(x, b1, A1);
    gmid<2><<<gm, blk, 0, stream>>>(A1, b2, A2);
    gmid<3><<<gm, blk, 0, stream>>>(A2, b3, A1);
    g4<<<gm, blk, 0, stream>>>(A1, b4, out);
}